// Round 10
// baseline (321.905 us; speedup 1.0000x reference)
//
#include <hip/hip_runtime.h>
#include <hip/hip_bf16.h>
#include <stdint.h>

#define DIN   1024
#define DOUT  1024
#define NHEAD 16
#define HDIM  64
#define SEQL  2048
#define BSZ   4
#define MTOT  (BSZ*SEQL)   // 8192
#define KDIM  1024

typedef __bf16 bf16x8 __attribute__((ext_vector_type(8)));
typedef float  f32x4  __attribute__((ext_vector_type(4)));

__device__ __forceinline__ f32x4 mfma16(bf16x8 a, bf16x8 b, f32x4 c) {
    return __builtin_amdgcn_mfma_f32_16x16x32_bf16(a, b, c, 0, 0, 0);
}

__device__ __forceinline__ void gl_lds16(const void* gsrc, void* ldst) {
    __builtin_amdgcn_global_load_lds(
        (const __attribute__((address_space(1))) uint32_t*)gsrc,
        (__attribute__((address_space(3))) uint32_t*)ldst, 16, 0, 0);
}

__device__ __forceinline__ unsigned short f2bf(float f) {
    union { __hip_bfloat16 h; unsigned short u; } cv;
    cv.h = __float2bfloat16(f);
    return cv.u;
}

// ---------------- fp32 -> bf16 elementwise (vectorized) ----------------
__global__ void cvt_bf16(const float4* __restrict__ in, ushort4* __restrict__ out, int n4) {
    int idx = blockIdx.x * blockDim.x + threadIdx.x;
    int stride = gridDim.x * blockDim.x;
    for (int i = idx; i < n4; i += stride) {
        float4 v = in[i];
        ushort4 o;
        o.x = f2bf(v.x); o.y = f2bf(v.y); o.z = f2bf(v.z); o.w = f2bf(v.w);
        out[i] = o;
    }
}

// ---- transpose + convert 3x W[1024][1024] f32 -> one Wt3[3072][1024] bf16 ----
__global__ void transpose_cvt3(const float* __restrict__ W0, const float* __restrict__ W1,
                               const float* __restrict__ W2, __hip_bfloat16* __restrict__ Wt3) {
    __shared__ __hip_bfloat16 t[32][33];
    const int tx = threadIdx.x, ty = threadIdx.y;   // (32, 8)
    const int bx = blockIdx.x, by = blockIdx.y, z = blockIdx.z;
    const float* W = (z == 0) ? W0 : (z == 1) ? W1 : W2;
    __hip_bfloat16* Wt = Wt3 + (size_t)z * DOUT * DIN;
#pragma unroll
    for (int r = 0; r < 4; ++r)
        t[ty + 8*r][tx] = __float2bfloat16(W[(size_t)(by*32 + ty + 8*r) * DOUT + bx*32 + tx]);
    __syncthreads();
#pragma unroll
    for (int r = 0; r < 4; ++r)
        Wt[(size_t)(bx*32 + ty + 8*r) * DIN + by*32 + tx] = t[tx][ty + 8*r];
}

__global__ void transpose_cvt(const float* __restrict__ W, __hip_bfloat16* __restrict__ Wt) {
    __shared__ __hip_bfloat16 t[32][33];
    const int tx = threadIdx.x, ty = threadIdx.y;
    const int bx = blockIdx.x, by = blockIdx.y;
#pragma unroll
    for (int r = 0; r < 4; ++r)
        t[ty + 8*r][tx] = __float2bfloat16(W[(size_t)(by*32 + ty + 8*r) * DOUT + bx*32 + tx]);
    __syncthreads();
#pragma unroll
    for (int r = 0; r < 4; ++r)
        Wt[(size_t)(bx*32 + ty + 8*r) * DIN + by*32 + tx] = t[tx][ty + 8*r];
}

// ---------------- 128x128-tile MFMA GEMM (256 threads, 4 waves, BK=32) ----------------
// EPI 0 (QK, swapped mfma -> C^T fragments, packed 8B stores)
// EPI 1 (V, normal mfma -> V^T packed seq stores)
// EPI 2 (out-proj, swapped mfma, packed 16B f32 stores)
// NOTE: 256-thread blocks only (512-thread blocks get a 128-VGPR budget, R5-R7).
template <int EPI>
__global__ __launch_bounds__(256)
void gemm_mfma(const __hip_bfloat16* __restrict__ A,
               const __hip_bfloat16* __restrict__ Bt,
               const float* __restrict__ b0, const float* __restrict__ b1,
               void* __restrict__ o0, void* __restrict__ o1,
               float scale)
{
    __shared__ alignas(16) __hip_bfloat16 As[2][4][128][8];
    __shared__ alignas(16) __hip_bfloat16 Bs[2][4][128][8];

    const int tid  = threadIdx.x;
    const int w    = tid >> 6;
    const int lane = tid & 63;
    const int g    = lane >> 4;
    const int r    = lane & 15;
    const int wr   = w >> 1, wc = w & 1;

    const int row0 = blockIdx.y * 128;
    const int col0 = blockIdx.x * 128;

    f32x4 acc[4][4];
#pragma unroll
    for (int m = 0; m < 4; ++m)
#pragma unroll
        for (int n = 0; n < 4; ++n) acc[m][n] = (f32x4)0.0f;

    auto stage = [&](int buf, int kt) {
        const __hip_bfloat16* ga = A  + (size_t)(row0 + lane) * KDIM + kt*32 + 8*w;
        const __hip_bfloat16* gb = Bt + (size_t)(col0 + lane) * KDIM + kt*32 + 8*w;
        gl_lds16(ga,            &As[buf][w][0][0]);
        gl_lds16(ga + 64*KDIM,  &As[buf][w][64][0]);
        gl_lds16(gb,            &Bs[buf][w][0][0]);
        gl_lds16(gb + 64*KDIM,  &Bs[buf][w][64][0]);
    };

    stage(0, 0);
    __syncthreads();

    const int NKT = KDIM / 32;
    for (int kt = 0; kt < NKT; ++kt) {
        const int cur = kt & 1;
        if (kt + 1 < NKT) stage(cur ^ 1, kt + 1);

        bf16x8 af[4], bfr[4];
#pragma unroll
        for (int m = 0; m < 4; ++m)
            af[m] = *reinterpret_cast<const bf16x8*>(&As[cur][g][64*wr + 16*m + r][0]);
#pragma unroll
        for (int n = 0; n < 4; ++n)
            bfr[n] = *reinterpret_cast<const bf16x8*>(&Bs[cur][g][64*wc + 16*n + r][0]);

#pragma unroll
        for (int m = 0; m < 4; ++m)
#pragma unroll
            for (int n = 0; n < 4; ++n) {
                if (EPI == 1) acc[m][n] = mfma16(af[m], bfr[n], acc[m][n]);  // C
                else          acc[m][n] = mfma16(bfr[n], af[m], acc[m][n]);  // C^T
            }

        __syncthreads();
    }

    if (EPI == 0) {
        const int slab = col0 >> 10;                    // block-uniform
        const float* bp = (slab == 0) ? b0 : b1;
        __hip_bfloat16* op = (__hip_bfloat16*)((slab == 0) ? o0 : o1);
        const float sc = (slab == 0) ? scale : 1.0f;
#pragma unroll
        for (int m = 0; m < 4; ++m) {
            const int rowg = row0 + 64*wr + 16*m + r;
            const int bb = rowg >> 11, sq = rowg & (SEQL-1);
#pragma unroll
            for (int n = 0; n < 4; ++n) {
                const int c2 = (col0 & 1023) + 64*wc + 16*n + 4*g;
                const int hh = c2 >> 6, dd = c2 & (HDIM-1);
                const float4 bv4 = *reinterpret_cast<const float4*>(&bp[c2]);
                ushort4 ov;
                ov.x = f2bf((acc[m][n][0] + bv4.x) * sc);
                ov.y = f2bf((acc[m][n][1] + bv4.y) * sc);
                ov.z = f2bf((acc[m][n][2] + bv4.z) * sc);
                ov.w = f2bf((acc[m][n][3] + bv4.w) * sc);
                *reinterpret_cast<ushort4*>(
                    &op[(((size_t)(bb*NHEAD + hh) * SEQL + sq) << 6) + dd]) = ov;
            }
        }
    } else if (EPI == 1) {
#pragma unroll
        for (int n = 0; n < 4; ++n) {
            const int colg = col0 + 64*wc + 16*n + r;
            const int hh = colg >> 6, dd = colg & (HDIM-1);
            const float bv_ = b0[colg];
#pragma unroll
            for (int m = 0; m < 4; ++m) {
                const int rowg0 = row0 + 64*wr + 16*m + 4*g;
                const int bb = rowg0 >> 11, sq0 = rowg0 & (SEQL-1);
                ushort4 ov;
                ov.x = f2bf(acc[m][n][0] + bv_);
                ov.y = f2bf(acc[m][n][1] + bv_);
                ov.z = f2bf(acc[m][n][2] + bv_);
                ov.w = f2bf(acc[m][n][3] + bv_);
                *reinterpret_cast<ushort4*>(
                    &((__hip_bfloat16*)o0)[((size_t)(bb*NHEAD + hh) * HDIM + dd) * SEQL + sq0]) = ov;
            }
        }
    } else {
#pragma unroll
        for (int m = 0; m < 4; ++m) {
            const int rowg = row0 + 64*wr + 16*m + r;
#pragma unroll
            for (int n = 0; n < 4; ++n) {
                const int colg0 = col0 + 64*wc + 16*n + 4*g;
                const float4 bv4 = *reinterpret_cast<const float4*>(&b0[colg0]);
                float4 ov;
                ov.x = acc[m][n][0] + bv4.x;
                ov.y = acc[m][n][1] + bv4.y;
                ov.z = acc[m][n][2] + bv4.z;
                ov.w = acc[m][n][3] + bv4.w;
                *reinterpret_cast<float4*>(&((float*)o0)[(size_t)rowg * DOUT + colg0]) = ov;
            }
        }
    }
}

// ---------------- causal flash attention (1-wave blocks, R9 inner body) ----------------
// Q,K: [B,H,S,64] bf16 (Q pre-scaled by log2e/8).  Vt: [B,H,64,S] bf16.
// ctx: [B,S,H*64] bf16.
// ONE wave per block, 32 rows/wave, strip pair (sp, 63-sp); grid (32,64) = 2048
// uniform blocks. At VGPR~164 HW fits 3 waves/SIMD = 12 blocks/CU (vs 8 waves/CU
// with 4-wave blocks in R9) -> +50% latency-hiding residency. No barriers needed
// (Ps bounce is wave-private). V issued early, K double-buffered, setprio on MFMA.
__global__ __launch_bounds__(64)
void attn_fwd(const __hip_bfloat16* __restrict__ Q,
              const __hip_bfloat16* __restrict__ K,
              const __hip_bfloat16* __restrict__ Vt,
              __hip_bfloat16* __restrict__ ctx)
{
    __shared__ alignas(16) __hip_bfloat16 Ps[2][16][64];

    const int tid  = threadIdx.x;
    const int lane = tid & 63;
    const int g    = lane >> 4;
    const int r    = lane & 15;
    const int swz  = (r & 7) << 3;   // element-XOR within a 64-elt (128B) row

    const int bh = blockIdx.y;
    const int b  = bh >> 4, h = bh & 15;

    const __hip_bfloat16* Qh = Q  + (size_t)bh * SEQL * HDIM;
    const __hip_bfloat16* Kh = K  + (size_t)bh * SEQL * HDIM;
    const __hip_bfloat16* Vh = Vt + (size_t)bh * HDIM * SEQL;

    const int sp = blockIdx.x;   // 0..31

#pragma unroll 1
    for (int ti = 0; ti < 2; ++ti) {
        const int strip = ti ? (63 - sp) : sp;
        const int qb = strip * 32;

        bf16x8 qf[2][2];
#pragma unroll
        for (int m = 0; m < 2; ++m)
#pragma unroll
            for (int hh = 0; hh < 2; ++hh)
                qf[m][hh] = *reinterpret_cast<const bf16x8*>(
                    Qh + (size_t)(qb + 16*m + r) * HDIM + 32*hh + 8*g);

        f32x4 o[2][4];
        float mrow[2], lrow[2];
#pragma unroll
        for (int m = 0; m < 2; ++m) {
#pragma unroll
            for (int n = 0; n < 4; ++n) o[m][n] = (f32x4)0.0f;
            mrow[m] = -1e30f; lrow[m] = 0.0f;
        }

        const int nst = ((qb + 31) >> 6) + 1;

        bf16x8 kA[4][2], kB[4][2], vf[4][2];

        auto loadK = [&](bf16x8 (&kf)[4][2], int key0) __attribute__((always_inline)) {
#pragma unroll
            for (int c = 0; c < 4; ++c)
#pragma unroll
                for (int hh = 0; hh < 2; ++hh)
                    kf[c][hh] = *reinterpret_cast<const bf16x8*>(
                        Kh + (size_t)(key0 + 16*c + r) * HDIM + 32*hh + 8*g);
        };

        auto step = [&](bf16x8 (&KC)[4][2], bf16x8 (&KN)[4][2], int kt)
                        __attribute__((always_inline)) {
            const int key0 = kt * 64;

            // V for THIS step: issued first, consumed after softmax
#pragma unroll
            for (int n = 0; n < 4; ++n) {
                vf[n][0] = *reinterpret_cast<const bf16x8*>(
                    Vh + (size_t)(16*n + r) * SEQL + key0 + 8*g);
                vf[n][1] = *reinterpret_cast<const bf16x8*>(
                    Vh + (size_t)(16*n + r) * SEQL + key0 + 32 + 8*g);
            }
            // K for NEXT step: in flight across the whole step
            if (kt + 1 < nst) loadK(KN, key0 + 64);

            // S^T[key = key0+16c+4g+j][qrow = qb+16m+r]
            f32x4 s[2][4];
            __builtin_amdgcn_s_setprio(1);
#pragma unroll
            for (int m = 0; m < 2; ++m)
#pragma unroll
                for (int c = 0; c < 4; ++c) {
                    f32x4 t = (f32x4)0.0f;
                    t = mfma16(KC[c][0], qf[m][0], t);
                    t = mfma16(KC[c][1], qf[m][1], t);
                    s[m][c] = t;
                }
            __builtin_amdgcn_s_setprio(0);

            if (kt == nst - 1) {   // causal mask only in the boundary step
#pragma unroll
                for (int m = 0; m < 2; ++m) {
                    const int qrow = qb + 16*m + r;
#pragma unroll
                    for (int c = 0; c < 4; ++c) {
                        const int kb = key0 + 16*c + 4*g;
#pragma unroll
                        for (int j = 0; j < 4; ++j)
                            if (kb + j > qrow) s[m][c][j] = -1e30f;
                    }
                }
            }

#pragma unroll
            for (int m = 0; m < 2; ++m) {
                // row-max: in-reg tree (16 vals, one q-row) + 2 cross-lane hops
                float t0 = fmaxf(fmaxf(s[m][0][0], s[m][0][1]), fmaxf(s[m][0][2], s[m][0][3]));
                float t1 = fmaxf(fmaxf(s[m][1][0], s[m][1][1]), fmaxf(s[m][1][2], s[m][1][3]));
                float t2 = fmaxf(fmaxf(s[m][2][0], s[m][2][1]), fmaxf(s[m][2][2], s[m][2][3]));
                float t3 = fmaxf(fmaxf(s[m][3][0], s[m][3][1]), fmaxf(s[m][3][2], s[m][3][3]));
                float pm = fmaxf(fmaxf(t0, t1), fmaxf(t2, t3));
                pm = fmaxf(pm, __shfl_xor(pm, 16));
                pm = fmaxf(pm, __shfl_xor(pm, 32));

                // defer-max: rescale only when max grew materially (log2 domain)
                if (__any(pm > mrow[m] + 11.0f)) {
                    const float mnew = fmaxf(mrow[m], pm);
                    const float fac  = exp2f(mrow[m] - mnew);
                    mrow[m] = mnew;
                    lrow[m] *= fac;
#pragma unroll
                    for (int n = 0; n < 4; ++n) o[m][n] *= fac;
                }

                float p[4][4];
#pragma unroll
                for (int c = 0; c < 4; ++c)
#pragma unroll
                    for (int j = 0; j < 4; ++j)
                        p[c][j] = exp2f(s[m][c][j] - mrow[m]);

                float u0 = (p[0][0] + p[0][1]) + (p[0][2] + p[0][3]);
                float u1 = (p[1][0] + p[1][1]) + (p[1][2] + p[1][3]);
                float u2 = (p[2][0] + p[2][1]) + (p[2][2] + p[2][3]);
                float u3 = (p[3][0] + p[3][1]) + (p[3][2] + p[3][3]);
                float ps = (u0 + u1) + (u2 + u3);
                ps += __shfl_xor(ps, 16);
                ps += __shfl_xor(ps, 32);
                lrow[m] += ps;

                // pack P row-fragment: 4 bf16 per c -> swizzled ds_write_b64
#pragma unroll
                for (int c = 0; c < 4; ++c) {
                    ushort4 pk4;
                    pk4.x = f2bf(p[c][0]); pk4.y = f2bf(p[c][1]);
                    pk4.z = f2bf(p[c][2]); pk4.w = f2bf(p[c][3]);
                    *reinterpret_cast<ushort4*>(&Ps[m][r][(16*c + 4*g) ^ swz]) = pk4;
                }
            }

            // P fragments (swizzled b128 reads) + PV as mfma(V^T, P^T)
            bf16x8 pf[2][2];
#pragma unroll
            for (int m = 0; m < 2; ++m)
#pragma unroll
                for (int hh = 0; hh < 2; ++hh)
                    pf[m][hh] = *reinterpret_cast<const bf16x8*>(
                        &Ps[m][r][(32*hh + 8*g) ^ swz]);

            __builtin_amdgcn_s_setprio(1);
#pragma unroll
            for (int n = 0; n < 4; ++n)
#pragma unroll
                for (int m = 0; m < 2; ++m) {
                    o[m][n] = mfma16(vf[n][0], pf[m][0], o[m][n]);
                    o[m][n] = mfma16(vf[n][1], pf[m][1], o[m][n]);
                }
            __builtin_amdgcn_s_setprio(0);
        };

        loadK(kA, 0);
        int kt = 0;
        while (true) {
            step(kA, kB, kt); if (++kt >= nst) break;
            step(kB, kA, kt); if (++kt >= nst) break;
        }

        // epilogue: O^T fragment -> ctx row-major; per-lane row, 8B packed stores
#pragma unroll
        for (int m = 0; m < 2; ++m) {
            const float inv = 1.0f / lrow[m];
            const size_t rowbase = (size_t)(b*SEQL + qb + 16*m + r) * DOUT + h*HDIM;
#pragma unroll
            for (int n = 0; n < 4; ++n) {
                ushort4 ov;
                ov.x = f2bf(o[m][n][0] * inv); ov.y = f2bf(o[m][n][1] * inv);
                ov.z = f2bf(o[m][n][2] * inv); ov.w = f2bf(o[m][n][3] * inv);
                *reinterpret_cast<ushort4*>(&ctx[rowbase + 16*n + 4*g]) = ov;
            }
        }
    }
}

extern "C" void kernel_launch(void* const* d_in, const int* in_sizes, int n_in,
                              void* d_out, int out_size, void* d_ws, size_t ws_size,
                              hipStream_t stream) {
    const float* x  = (const float*)d_in[0];
    const float* Wq = (const float*)d_in[1];
    const float* bq = (const float*)d_in[2];
    const float* Wk = (const float*)d_in[3];
    const float* bk = (const float*)d_in[4];
    const float* Wv = (const float*)d_in[5];
    const float* bv = (const float*)d_in[6];
    const float* Wo = (const float*)d_in[7];
    const float* bo = (const float*)d_in[8];
    float* out = (float*)d_out;
    (void)in_sizes; (void)n_in; (void)out_size; (void)ws_size;

    char* ws = (char*)d_ws;
    __hip_bfloat16* xb  = (__hip_bfloat16*)ws;                       // 16 MB
    __hip_bfloat16* Wt3 = (__hip_bfloat16*)(ws + (16u << 20));       // 6 MB (Q,K,V slabs)
    __hip_bfloat16* Wot = (__hip_bfloat16*)(ws + (22u << 20));       // 2 MB
    __hip_bfloat16* Qb  = (__hip_bfloat16*)(ws + (24u << 20));       // 16 MB
    __hip_bfloat16* Kb  = Qb + (size_t)MTOT * DOUT;                  // 16 MB
    __hip_bfloat16* Vtb = Kb + (size_t)MTOT * DOUT;                  // 16 MB
    __hip_bfloat16* ctx = xb;  // alias: xb dead after the QKV GEMMs

    cvt_bf16<<<2048, 256, 0, stream>>>((const float4*)x, (ushort4*)xb, MTOT * DIN / 4);

    dim3 tb(32, 8);
    transpose_cvt3<<<dim3(32, 32, 3), tb, 0, stream>>>(Wq, Wk, Wv, Wt3);
    transpose_cvt <<<dim3(32, 32),    tb, 0, stream>>>(Wo, Wot);

    // QK fused GEMM (N=2048, swapped orientation). Q scale folds 1/8 * log2(e).
    dim3 gqk(2*DOUT / 128, MTOT / 128);  // (16, 64)
    gemm_mfma<0><<<gqk, 256, 0, stream>>>(xb, Wt3, bq, bk, Qb, Kb,
                                          0.125f * 1.44269504088896f);
    // V GEMM (N=1024, normal orientation) -> V^T
    dim3 gv(DOUT / 128, MTOT / 128);     // (8, 64)
    gemm_mfma<1><<<gv, 256, 0, stream>>>(xb, Wt3 + (size_t)2*DOUT*DIN, bv, nullptr,
                                         Vtb, nullptr, 1.0f);

    dim3 ag(32, BSZ * NHEAD);  // 32 strip-pair blocks (1 wave each) x 64 (b,h)
    attn_fwd<<<ag, 64, 0, stream>>>(Qb, Kb, Vtb, ctx);

    // out-proj (swapped orientation, f32x4 stores)
    gemm_mfma<2><<<gv, 256, 0, stream>>>(ctx, Wot, bo, nullptr,
                                         out, nullptr, 1.0f);
}

// Round 11
// 302.402 us; speedup vs baseline: 1.0645x; 1.0645x over previous
//
#include <hip/hip_runtime.h>
#include <hip/hip_bf16.h>
#include <stdint.h>

#define DIN   1024
#define DOUT  1024
#define NHEAD 16
#define HDIM  64
#define SEQL  2048
#define BSZ   4
#define MTOT  (BSZ*SEQL)   // 8192
#define KDIM  1024

typedef __bf16 bf16x8 __attribute__((ext_vector_type(8)));
typedef float  f32x4  __attribute__((ext_vector_type(4)));

__device__ __forceinline__ f32x4 mfma16(bf16x8 a, bf16x8 b, f32x4 c) {
    return __builtin_amdgcn_mfma_f32_16x16x32_bf16(a, b, c, 0, 0, 0);
}

__device__ __forceinline__ void gl_lds16(const void* gsrc, void* ldst) {
    __builtin_amdgcn_global_load_lds(
        (const __attribute__((address_space(1))) uint32_t*)gsrc,
        (__attribute__((address_space(3))) uint32_t*)ldst, 16, 0, 0);
}

__device__ __forceinline__ unsigned short f2bf(float f) {
    union { __hip_bfloat16 h; unsigned short u; } cv;
    cv.h = __float2bfloat16(f);
    return cv.u;
}

// ---------------- fp32 -> bf16 elementwise (vectorized) ----------------
__global__ void cvt_bf16(const float4* __restrict__ in, ushort4* __restrict__ out, int n4) {
    int idx = blockIdx.x * blockDim.x + threadIdx.x;
    int stride = gridDim.x * blockDim.x;
    for (int i = idx; i < n4; i += stride) {
        float4 v = in[i];
        ushort4 o;
        o.x = f2bf(v.x); o.y = f2bf(v.y); o.z = f2bf(v.z); o.w = f2bf(v.w);
        out[i] = o;
    }
}

// ---- transpose + convert 3x W[1024][1024] f32 -> one Wt3[3072][1024] bf16 ----
__global__ void transpose_cvt3(const float* __restrict__ W0, const float* __restrict__ W1,
                               const float* __restrict__ W2, __hip_bfloat16* __restrict__ Wt3) {
    __shared__ __hip_bfloat16 t[32][33];
    const int tx = threadIdx.x, ty = threadIdx.y;   // (32, 8)
    const int bx = blockIdx.x, by = blockIdx.y, z = blockIdx.z;
    const float* W = (z == 0) ? W0 : (z == 1) ? W1 : W2;
    __hip_bfloat16* Wt = Wt3 + (size_t)z * DOUT * DIN;
#pragma unroll
    for (int r = 0; r < 4; ++r)
        t[ty + 8*r][tx] = __float2bfloat16(W[(size_t)(by*32 + ty + 8*r) * DOUT + bx*32 + tx]);
    __syncthreads();
#pragma unroll
    for (int r = 0; r < 4; ++r)
        Wt[(size_t)(bx*32 + ty + 8*r) * DIN + by*32 + tx] = t[tx][ty + 8*r];
}

__global__ void transpose_cvt(const float* __restrict__ W, __hip_bfloat16* __restrict__ Wt) {
    __shared__ __hip_bfloat16 t[32][33];
    const int tx = threadIdx.x, ty = threadIdx.y;
    const int bx = blockIdx.x, by = blockIdx.y;
#pragma unroll
    for (int r = 0; r < 4; ++r)
        t[ty + 8*r][tx] = __float2bfloat16(W[(size_t)(by*32 + ty + 8*r) * DOUT + bx*32 + tx]);
    __syncthreads();
#pragma unroll
    for (int r = 0; r < 4; ++r)
        Wt[(size_t)(bx*32 + ty + 8*r) * DIN + by*32 + tx] = t[tx][ty + 8*r];
}

// ---------------- 128x128-tile MFMA GEMM (256 threads, 4 waves, BK=32) ----------------
// EPI 0 (QK, swapped mfma -> C^T fragments, packed 8B stores)
// EPI 1 (V, normal mfma -> V^T packed seq stores)
// EPI 2 (out-proj, swapped mfma, packed 16B f32 stores)
// NOTE: 256-thread blocks only (512-thread blocks get a 128-VGPR budget, R5-R7).
template <int EPI>
__global__ __launch_bounds__(256)
void gemm_mfma(const __hip_bfloat16* __restrict__ A,
               const __hip_bfloat16* __restrict__ Bt,
               const float* __restrict__ b0, const float* __restrict__ b1,
               void* __restrict__ o0, void* __restrict__ o1,
               float scale)
{
    __shared__ alignas(16) __hip_bfloat16 As[2][4][128][8];
    __shared__ alignas(16) __hip_bfloat16 Bs[2][4][128][8];

    const int tid  = threadIdx.x;
    const int w    = tid >> 6;
    const int lane = tid & 63;
    const int g    = lane >> 4;
    const int r    = lane & 15;
    const int wr   = w >> 1, wc = w & 1;

    const int row0 = blockIdx.y * 128;
    const int col0 = blockIdx.x * 128;

    f32x4 acc[4][4];
#pragma unroll
    for (int m = 0; m < 4; ++m)
#pragma unroll
        for (int n = 0; n < 4; ++n) acc[m][n] = (f32x4)0.0f;

    auto stage = [&](int buf, int kt) {
        const __hip_bfloat16* ga = A  + (size_t)(row0 + lane) * KDIM + kt*32 + 8*w;
        const __hip_bfloat16* gb = Bt + (size_t)(col0 + lane) * KDIM + kt*32 + 8*w;
        gl_lds16(ga,            &As[buf][w][0][0]);
        gl_lds16(ga + 64*KDIM,  &As[buf][w][64][0]);
        gl_lds16(gb,            &Bs[buf][w][0][0]);
        gl_lds16(gb + 64*KDIM,  &Bs[buf][w][64][0]);
    };

    stage(0, 0);
    __syncthreads();

    const int NKT = KDIM / 32;
    for (int kt = 0; kt < NKT; ++kt) {
        const int cur = kt & 1;
        if (kt + 1 < NKT) stage(cur ^ 1, kt + 1);

        bf16x8 af[4], bfr[4];
#pragma unroll
        for (int m = 0; m < 4; ++m)
            af[m] = *reinterpret_cast<const bf16x8*>(&As[cur][g][64*wr + 16*m + r][0]);
#pragma unroll
        for (int n = 0; n < 4; ++n)
            bfr[n] = *reinterpret_cast<const bf16x8*>(&Bs[cur][g][64*wc + 16*n + r][0]);

#pragma unroll
        for (int m = 0; m < 4; ++m)
#pragma unroll
            for (int n = 0; n < 4; ++n) {
                if (EPI == 1) acc[m][n] = mfma16(af[m], bfr[n], acc[m][n]);  // C
                else          acc[m][n] = mfma16(bfr[n], af[m], acc[m][n]);  // C^T
            }

        __syncthreads();
    }

    if (EPI == 0) {
        const int slab = col0 >> 10;                    // block-uniform
        const float* bp = (slab == 0) ? b0 : b1;
        __hip_bfloat16* op = (__hip_bfloat16*)((slab == 0) ? o0 : o1);
        const float sc = (slab == 0) ? scale : 1.0f;
#pragma unroll
        for (int m = 0; m < 4; ++m) {
            const int rowg = row0 + 64*wr + 16*m + r;
            const int bb = rowg >> 11, sq = rowg & (SEQL-1);
#pragma unroll
            for (int n = 0; n < 4; ++n) {
                const int c2 = (col0 & 1023) + 64*wc + 16*n + 4*g;
                const int hh = c2 >> 6, dd = c2 & (HDIM-1);
                const float4 bv4 = *reinterpret_cast<const float4*>(&bp[c2]);
                ushort4 ov;
                ov.x = f2bf((acc[m][n][0] + bv4.x) * sc);
                ov.y = f2bf((acc[m][n][1] + bv4.y) * sc);
                ov.z = f2bf((acc[m][n][2] + bv4.z) * sc);
                ov.w = f2bf((acc[m][n][3] + bv4.w) * sc);
                *reinterpret_cast<ushort4*>(
                    &op[(((size_t)(bb*NHEAD + hh) * SEQL + sq) << 6) + dd]) = ov;
            }
        }
    } else if (EPI == 1) {
#pragma unroll
        for (int n = 0; n < 4; ++n) {
            const int colg = col0 + 64*wc + 16*n + r;
            const int hh = colg >> 6, dd = colg & (HDIM-1);
            const float bv_ = b0[colg];
#pragma unroll
            for (int m = 0; m < 4; ++m) {
                const int rowg0 = row0 + 64*wr + 16*m + 4*g;
                const int bb = rowg0 >> 11, sq0 = rowg0 & (SEQL-1);
                ushort4 ov;
                ov.x = f2bf(acc[m][n][0] + bv_);
                ov.y = f2bf(acc[m][n][1] + bv_);
                ov.z = f2bf(acc[m][n][2] + bv_);
                ov.w = f2bf(acc[m][n][3] + bv_);
                *reinterpret_cast<ushort4*>(
                    &((__hip_bfloat16*)o0)[((size_t)(bb*NHEAD + hh) * HDIM + dd) * SEQL + sq0]) = ov;
            }
        }
    } else {
#pragma unroll
        for (int m = 0; m < 4; ++m) {
            const int rowg = row0 + 64*wr + 16*m + r;
#pragma unroll
            for (int n = 0; n < 4; ++n) {
                const int colg0 = col0 + 64*wc + 16*n + 4*g;
                const float4 bv4 = *reinterpret_cast<const float4*>(&b0[colg0]);
                float4 ov;
                ov.x = acc[m][n][0] + bv4.x;
                ov.y = acc[m][n][1] + bv4.y;
                ov.z = acc[m][n][2] + bv4.z;
                ov.w = acc[m][n][3] + bv4.w;
                *reinterpret_cast<float4*>(&((float*)o0)[(size_t)rowg * DOUT + colg0]) = ov;
            }
        }
    }
}

// ---------------- causal flash attention (R9 body + XCD-local grid) ----------------
// Q,K: [B,H,S,64] bf16 (Q pre-scaled by log2e/8).  Vt: [B,H,64,S] bf16.
// ctx: [B,S,H*64] bf16.
// 4 waves/block, 32 rows/wave, strip pair (sp, 63-sp) per wave.
// GRID (64, 8): bx = bh, by = strip-group. Linear block id = bh + 64*by, so
// id % 8 = bh % 8 -> all 8 blocks sharing one bh's K/V land on the SAME XCD
// (R9's (8,64) grid put them on 8 DIFFERENT XCDs; R10 showed 3x HBM overfetch
// when same-bh co-location is lost). 512 KB K/V per bh stays L2-resident.
__global__ __launch_bounds__(256)
void attn_fwd(const __hip_bfloat16* __restrict__ Q,
              const __hip_bfloat16* __restrict__ K,
              const __hip_bfloat16* __restrict__ Vt,
              __hip_bfloat16* __restrict__ ctx)
{
    __shared__ alignas(16) __hip_bfloat16 Ps[4][2][16][64];

    const int tid  = threadIdx.x;
    const int w    = tid >> 6;
    const int lane = tid & 63;
    const int g    = lane >> 4;
    const int r    = lane & 15;
    const int swz  = (r & 7) << 3;   // element-XOR within a 64-elt (128B) row

    const int bh = blockIdx.x;       // XCD-local: id%8 == bh%8
    const int b  = bh >> 4, h = bh & 15;

    const __hip_bfloat16* Qh = Q  + (size_t)bh * SEQL * HDIM;
    const __hip_bfloat16* Kh = K  + (size_t)bh * SEQL * HDIM;
    const __hip_bfloat16* Vh = Vt + (size_t)bh * HDIM * SEQL;

    const int sp = blockIdx.y * 4 + w;   // 0..31

#pragma unroll 1
    for (int ti = 0; ti < 2; ++ti) {
        const int strip = ti ? (63 - sp) : sp;
        const int qb = strip * 32;

        bf16x8 qf[2][2];
#pragma unroll
        for (int m = 0; m < 2; ++m)
#pragma unroll
            for (int hh = 0; hh < 2; ++hh)
                qf[m][hh] = *reinterpret_cast<const bf16x8*>(
                    Qh + (size_t)(qb + 16*m + r) * HDIM + 32*hh + 8*g);

        f32x4 o[2][4];
        float mrow[2], lrow[2];
#pragma unroll
        for (int m = 0; m < 2; ++m) {
#pragma unroll
            for (int n = 0; n < 4; ++n) o[m][n] = (f32x4)0.0f;
            mrow[m] = -1e30f; lrow[m] = 0.0f;
        }

        const int nst = ((qb + 31) >> 6) + 1;

        bf16x8 kA[4][2], kB[4][2], vf[4][2];

        auto loadK = [&](bf16x8 (&kf)[4][2], int key0) __attribute__((always_inline)) {
#pragma unroll
            for (int c = 0; c < 4; ++c)
#pragma unroll
                for (int hh = 0; hh < 2; ++hh)
                    kf[c][hh] = *reinterpret_cast<const bf16x8*>(
                        Kh + (size_t)(key0 + 16*c + r) * HDIM + 32*hh + 8*g);
        };

        auto step = [&](bf16x8 (&KC)[4][2], bf16x8 (&KN)[4][2], int kt)
                        __attribute__((always_inline)) {
            const int key0 = kt * 64;

            // V for THIS step: issued first, consumed after softmax
#pragma unroll
            for (int n = 0; n < 4; ++n) {
                vf[n][0] = *reinterpret_cast<const bf16x8*>(
                    Vh + (size_t)(16*n + r) * SEQL + key0 + 8*g);
                vf[n][1] = *reinterpret_cast<const bf16x8*>(
                    Vh + (size_t)(16*n + r) * SEQL + key0 + 32 + 8*g);
            }
            // K for NEXT step: in flight across the whole step
            if (kt + 1 < nst) loadK(KN, key0 + 64);

            // S^T[key = key0+16c+4g+j][qrow = qb+16m+r]
            f32x4 s[2][4];
            __builtin_amdgcn_s_setprio(1);
#pragma unroll
            for (int m = 0; m < 2; ++m)
#pragma unroll
                for (int c = 0; c < 4; ++c) {
                    f32x4 t = (f32x4)0.0f;
                    t = mfma16(KC[c][0], qf[m][0], t);
                    t = mfma16(KC[c][1], qf[m][1], t);
                    s[m][c] = t;
                }
            __builtin_amdgcn_s_setprio(0);

            if (kt == nst - 1) {   // causal mask only in the boundary step
#pragma unroll
                for (int m = 0; m < 2; ++m) {
                    const int qrow = qb + 16*m + r;
#pragma unroll
                    for (int c = 0; c < 4; ++c) {
                        const int kb = key0 + 16*c + 4*g;
#pragma unroll
                        for (int j = 0; j < 4; ++j)
                            if (kb + j > qrow) s[m][c][j] = -1e30f;
                    }
                }
            }

#pragma unroll
            for (int m = 0; m < 2; ++m) {
                // row-max: in-reg tree (16 vals, one q-row) + 2 cross-lane hops
                float t0 = fmaxf(fmaxf(s[m][0][0], s[m][0][1]), fmaxf(s[m][0][2], s[m][0][3]));
                float t1 = fmaxf(fmaxf(s[m][1][0], s[m][1][1]), fmaxf(s[m][1][2], s[m][1][3]));
                float t2 = fmaxf(fmaxf(s[m][2][0], s[m][2][1]), fmaxf(s[m][2][2], s[m][2][3]));
                float t3 = fmaxf(fmaxf(s[m][3][0], s[m][3][1]), fmaxf(s[m][3][2], s[m][3][3]));
                float pm = fmaxf(fmaxf(t0, t1), fmaxf(t2, t3));
                pm = fmaxf(pm, __shfl_xor(pm, 16));
                pm = fmaxf(pm, __shfl_xor(pm, 32));

                // defer-max: rescale only when max grew materially (log2 domain)
                if (__any(pm > mrow[m] + 11.0f)) {
                    const float mnew = fmaxf(mrow[m], pm);
                    const float fac  = exp2f(mrow[m] - mnew);
                    mrow[m] = mnew;
                    lrow[m] *= fac;
#pragma unroll
                    for (int n = 0; n < 4; ++n) o[m][n] *= fac;
                }

                float p[4][4];
#pragma unroll
                for (int c = 0; c < 4; ++c)
#pragma unroll
                    for (int j = 0; j < 4; ++j)
                        p[c][j] = exp2f(s[m][c][j] - mrow[m]);

                float u0 = (p[0][0] + p[0][1]) + (p[0][2] + p[0][3]);
                float u1 = (p[1][0] + p[1][1]) + (p[1][2] + p[1][3]);
                float u2 = (p[2][0] + p[2][1]) + (p[2][2] + p[2][3]);
                float u3 = (p[3][0] + p[3][1]) + (p[3][2] + p[3][3]);
                float ps = (u0 + u1) + (u2 + u3);
                ps += __shfl_xor(ps, 16);
                ps += __shfl_xor(ps, 32);
                lrow[m] += ps;

                // pack P row-fragment: 4 bf16 per c -> swizzled ds_write_b64
#pragma unroll
                for (int c = 0; c < 4; ++c) {
                    ushort4 pk4;
                    pk4.x = f2bf(p[c][0]); pk4.y = f2bf(p[c][1]);
                    pk4.z = f2bf(p[c][2]); pk4.w = f2bf(p[c][3]);
                    *reinterpret_cast<ushort4*>(&Ps[w][m][r][(16*c + 4*g) ^ swz]) = pk4;
                }
            }

            // P fragments (swizzled b128 reads) + PV as mfma(V^T, P^T)
            bf16x8 pf[2][2];
#pragma unroll
            for (int m = 0; m < 2; ++m)
#pragma unroll
                for (int hh = 0; hh < 2; ++hh)
                    pf[m][hh] = *reinterpret_cast<const bf16x8*>(
                        &Ps[w][m][r][(32*hh + 8*g) ^ swz]);

            __builtin_amdgcn_s_setprio(1);
#pragma unroll
            for (int n = 0; n < 4; ++n)
#pragma unroll
                for (int m = 0; m < 2; ++m) {
                    o[m][n] = mfma16(vf[n][0], pf[m][0], o[m][n]);
                    o[m][n] = mfma16(vf[n][1], pf[m][1], o[m][n]);
                }
            __builtin_amdgcn_s_setprio(0);
        };

        loadK(kA, 0);
        int kt = 0;
        while (true) {
            step(kA, kB, kt); if (++kt >= nst) break;
            step(kB, kA, kt); if (++kt >= nst) break;
        }

        // epilogue: O^T fragment -> ctx row-major; per-lane row, 8B packed stores
#pragma unroll
        for (int m = 0; m < 2; ++m) {
            const float inv = 1.0f / lrow[m];
            const size_t rowbase = (size_t)(b*SEQL + qb + 16*m + r) * DOUT + h*HDIM;
#pragma unroll
            for (int n = 0; n < 4; ++n) {
                ushort4 ov;
                ov.x = f2bf(o[m][n][0] * inv); ov.y = f2bf(o[m][n][1] * inv);
                ov.z = f2bf(o[m][n][2] * inv); ov.w = f2bf(o[m][n][3] * inv);
                *reinterpret_cast<ushort4*>(&ctx[rowbase + 16*n + 4*g]) = ov;
            }
        }
    }
}

extern "C" void kernel_launch(void* const* d_in, const int* in_sizes, int n_in,
                              void* d_out, int out_size, void* d_ws, size_t ws_size,
                              hipStream_t stream) {
    const float* x  = (const float*)d_in[0];
    const float* Wq = (const float*)d_in[1];
    const float* bq = (const float*)d_in[2];
    const float* Wk = (const float*)d_in[3];
    const float* bk = (const float*)d_in[4];
    const float* Wv = (const float*)d_in[5];
    const float* bv = (const float*)d_in[6];
    const float* Wo = (const float*)d_in[7];
    const float* bo = (const float*)d_in[8];
    float* out = (float*)d_out;
    (void)in_sizes; (void)n_in; (void)out_size; (void)ws_size;

    char* ws = (char*)d_ws;
    __hip_bfloat16* xb  = (__hip_bfloat16*)ws;                       // 16 MB
    __hip_bfloat16* Wt3 = (__hip_bfloat16*)(ws + (16u << 20));       // 6 MB (Q,K,V slabs)
    __hip_bfloat16* Wot = (__hip_bfloat16*)(ws + (22u << 20));       // 2 MB
    __hip_bfloat16* Qb  = (__hip_bfloat16*)(ws + (24u << 20));       // 16 MB
    __hip_bfloat16* Kb  = Qb + (size_t)MTOT * DOUT;                  // 16 MB
    __hip_bfloat16* Vtb = Kb + (size_t)MTOT * DOUT;                  // 16 MB
    __hip_bfloat16* ctx = xb;  // alias: xb dead after the QKV GEMMs

    cvt_bf16<<<2048, 256, 0, stream>>>((const float4*)x, (ushort4*)xb, MTOT * DIN / 4);

    dim3 tb(32, 8);
    transpose_cvt3<<<dim3(32, 32, 3), tb, 0, stream>>>(Wq, Wk, Wv, Wt3);
    transpose_cvt <<<dim3(32, 32),    tb, 0, stream>>>(Wo, Wot);

    // QK fused GEMM (N=2048, swapped orientation). Q scale folds 1/8 * log2(e).
    dim3 gqk(2*DOUT / 128, MTOT / 128);  // (16, 64)
    gemm_mfma<0><<<gqk, 256, 0, stream>>>(xb, Wt3, bq, bk, Qb, Kb,
                                          0.125f * 1.44269504088896f);
    // V GEMM (N=1024, normal orientation) -> V^T
    dim3 gv(DOUT / 128, MTOT / 128);     // (8, 64)
    gemm_mfma<1><<<gv, 256, 0, stream>>>(xb, Wt3 + (size_t)2*DOUT*DIN, bv, nullptr,
                                         Vtb, nullptr, 1.0f);

    // attn: grid (bh, strip-group) so same-bh blocks share one XCD's L2
    dim3 ag(BSZ * NHEAD, 8);  // (64, 8)
    attn_fwd<<<ag, 256, 0, stream>>>(Qb, Kb, Vtb, ctx);

    // out-proj (swapped orientation, f32x4 stores)
    gemm_mfma<2><<<gv, 256, 0, stream>>>(ctx, Wot, bo, nullptr,
                                         out, nullptr, 1.0f);
}